// Round 4
// baseline (917.193 us; speedup 1.0000x reference)
//
#include <hip/hip_runtime.h>
#include <hip/hip_bf16.h>
#include <stdint.h>

#define DM   1024
#define DI   2048
#define NST  16
#define BSZ  4
#define SLEN 2048
#define MROWS (BSZ*SLEN)   // 8192
#define CHUNK 64
#define NCH  (SLEN/CHUNK)  // 32
#define DECAYF 0.95f
#define MB (size_t)1048576

typedef unsigned short u16;
typedef __attribute__((ext_vector_type(8))) short bf16x8;
typedef __attribute__((ext_vector_type(4))) float f32x4;

__device__ __forceinline__ float bf2f(u16 u) {
  union { unsigned u; float f; } v; v.u = ((unsigned)u) << 16; return v.f;
}
__device__ __forceinline__ u16 f2bf(float f) {
  union { float f; unsigned u; } v; v.f = f;
  unsigned r = v.u + 0x7fffu + ((v.u >> 16) & 1u);
  return (u16)(r >> 16);
}
__device__ __forceinline__ float silu_f(float v) { return v / (1.f + __expf(-v)); }

__device__ __forceinline__ void gload16(u16* lds, const u16* g) {
  __builtin_amdgcn_global_load_lds((const __attribute__((address_space(1))) void*)g,
                                   (__attribute__((address_space(3))) void*)lds, 16, 0, 0);
}

// ---- activation 3-split: rows of 3*K : [hi | hi | lo] ----
__global__ void split3_a(const float* __restrict__ in, u16* __restrict__ out, int K4, int n4) {
  int i = blockIdx.x * blockDim.x + threadIdx.x;
  if (i >= n4) return;
  int m = i / K4, kq = i % K4;
  int K = K4 * 4;
  float4 v = ((const float4*)in)[i];
  ushort4 hi, lo;
  hi.x = f2bf(v.x); hi.y = f2bf(v.y); hi.z = f2bf(v.z); hi.w = f2bf(v.w);
  lo.x = f2bf(v.x - bf2f(hi.x)); lo.y = f2bf(v.y - bf2f(hi.y));
  lo.z = f2bf(v.z - bf2f(hi.z)); lo.w = f2bf(v.w - bf2f(hi.w));
  size_t base = (size_t)m * (size_t)(3 * K);
  *(ushort4*)&out[base + kq * 4] = hi;
  *(ushort4*)&out[base + K + kq * 4] = hi;
  *(ushort4*)&out[base + 2 * K + kq * 4] = lo;
}

// ---- weight 3-split: rows of 3*K : [hi | lo | hi] ----
__global__ void split3_w(const float* __restrict__ in, u16* __restrict__ out, int K4, int n4) {
  int i = blockIdx.x * blockDim.x + threadIdx.x;
  if (i >= n4) return;
  int n = i / K4, kq = i % K4;
  int K = K4 * 4;
  float4 v = ((const float4*)in)[i];
  ushort4 hi, lo;
  hi.x = f2bf(v.x); hi.y = f2bf(v.y); hi.z = f2bf(v.z); hi.w = f2bf(v.w);
  lo.x = f2bf(v.x - bf2f(hi.x)); lo.y = f2bf(v.y - bf2f(hi.y));
  lo.z = f2bf(v.z - bf2f(hi.z)); lo.w = f2bf(v.w - bf2f(hi.w));
  size_t base = (size_t)n * (size_t)(3 * K);
  *(ushort4*)&out[base + kq * 4] = hi;
  *(ushort4*)&out[base + K + kq * 4] = lo;
  *(ushort4*)&out[base + 2 * K + kq * 4] = hi;
}

// ---------------- expB transposed: expBT[n][d] = exp(B_log[d][n]) ----------------
__global__ void expb_t(const float* __restrict__ B_log, float* __restrict__ expBT) {
  int i = blockIdx.x * blockDim.x + threadIdx.x;  // 32768
  int n = i >> 11, d = i & (DI - 1);
  expBT[i] = __expf(B_log[d * NST + n]);
}

// ---------------- bf16 MFMA GEMM: C[m,n] = sum_k A[m,k]*Bt[n,k] ----------------
template<int MODE>
__global__ __launch_bounds__(256) void gemm_bt(
    const u16* __restrict__ A, const u16* __restrict__ Bt,
    int M, int N, int K,
    float* __restrict__ Cf, float* __restrict__ Xi, float* __restrict__ Zs)
{
  __shared__ __align__(16) u16 sA[128 * 32];
  __shared__ __align__(16) u16 sB[128 * 32];
  const int tid  = threadIdx.x;
  const int lane = tid & 63;
  const int w    = tid >> 6;
  const int wr   = w >> 1, wc = w & 1;
  const int mBase = blockIdx.y * 128;
  const int nBase = blockIdx.x * 128;
  const int lr = lane & 15;
  const int lk = (lane >> 4) * 8;

  f32x4 acc[4][4];
  #pragma unroll
  for (int m = 0; m < 4; ++m)
    #pragma unroll
    for (int n = 0; n < 4; ++n)
      acc[m][n] = (f32x4){0.f, 0.f, 0.f, 0.f};

  for (int k0 = 0; k0 < K; k0 += 32) {
    #pragma unroll
    for (int j = 0; j < 2; ++j) {
      int chunk = j * 256 + tid;
      int row = chunk >> 2, kq = chunk & 3;
      gload16(&sA[chunk * 8], A + (size_t)(mBase + row) * K + k0 + kq * 8);
      gload16(&sB[chunk * 8], Bt + (size_t)(nBase + row) * K + k0 + kq * 8);
    }
    __syncthreads();
    bf16x8 af[4], bfr[4];
    #pragma unroll
    for (int m = 0; m < 4; ++m)
      af[m] = *(const bf16x8*)&sA[(wr * 64 + m * 16 + lr) * 32 + lk];
    #pragma unroll
    for (int n = 0; n < 4; ++n)
      bfr[n] = *(const bf16x8*)&sB[(wc * 64 + n * 16 + lr) * 32 + lk];
    #pragma unroll
    for (int m = 0; m < 4; ++m)
      #pragma unroll
      for (int n = 0; n < 4; ++n)
        acc[m][n] = __builtin_amdgcn_mfma_f32_16x16x32_bf16(af[m], bfr[n], acc[m][n], 0, 0, 0);
    __syncthreads();
  }

  const int rq = (lane >> 4) * 4;
  #pragma unroll
  for (int m = 0; m < 4; ++m) {
    #pragma unroll
    for (int n = 0; n < 4; ++n) {
      int col = nBase + wc * 64 + n * 16 + lr;
      #pragma unroll
      for (int r = 0; r < 4; ++r) {
        int row = mBase + wr * 64 + m * 16 + rq + r;
        float v = acc[m][n][r];
        if (MODE == 0) {
          Cf[(size_t)row * N + col] = v;
        } else {
          if (col < DI) Xi[(size_t)row * DI + col] = v;
          else          Zs[(size_t)row * DI + (col - DI)] = silu_f(v);
        }
      }
    }
  }
}

// ---------------- depthwise causal conv (w=4) + SiLU + chunked local scan ----------------
// grid: (DI/1024, NCH, BSZ), block 256, 4 d per thread. Xi fp32 in; Hl fp32 out.
__global__ __launch_bounds__(256) void conv_scan(
    const float* __restrict__ Xi, const float* __restrict__ convW, const float* __restrict__ convB,
    float* __restrict__ Hl, float* __restrict__ L)
{
  const int tid = threadIdx.x;
  const int d0 = (blockIdx.x * 256 + tid) * 4;
  const int ch = blockIdx.y;
  const int b  = blockIdx.z;
  const int t0 = ch * CHUNK;

  float w0[4], w1[4], w2[4], w3[4], cb[4];
  #pragma unroll
  for (int i = 0; i < 4; ++i) {
    float4 wv = ((const float4*)convW)[d0 + i];
    w0[i] = wv.x; w1[i] = wv.y; w2[i] = wv.z; w3[i] = wv.w;
    cb[i] = convB[d0 + i];
  }

  auto loadrow = [&](int t, float* dst) {
    if (t < 0) { dst[0] = dst[1] = dst[2] = dst[3] = 0.f; return; }
    float4 v = *(const float4*)&Xi[((size_t)(b * SLEN + t)) * DI + d0];
    dst[0] = v.x; dst[1] = v.y; dst[2] = v.z; dst[3] = v.w;
  };

  float xm3[4], xm2[4], xm1[4];
  loadrow(t0 - 3, xm3); loadrow(t0 - 2, xm2); loadrow(t0 - 1, xm1);

  float h[4] = {0.f, 0.f, 0.f, 0.f};
  for (int t = 0; t < CHUNK; ++t) {
    const size_t ro = ((size_t)(b * SLEN + t0 + t)) * DI + d0;
    float4 xv = *(const float4*)&Xi[ro];
    float xt[4] = {xv.x, xv.y, xv.z, xv.w};
    #pragma unroll
    for (int i = 0; i < 4; ++i) {
      float c = cb[i] + w0[i]*xm3[i] + w1[i]*xm2[i] + w2[i]*xm1[i] + w3[i]*xt[i];
      float xc = silu_f(c);
      h[i] = DECAYF * h[i] + xc;
    }
    float4 hv = {h[0], h[1], h[2], h[3]};
    *(float4*)&Hl[ro] = hv;
    #pragma unroll
    for (int i = 0; i < 4; ++i) { xm3[i] = xm2[i]; xm2[i] = xm1[i]; xm1[i] = xt[i]; }
  }
  float4 lo = {h[0], h[1], h[2], h[3]};
  *(float4*)&L[((size_t)(b * NCH + ch)) * DI + d0] = lo;
}

// ---------------- sequential chunk-carry ----------------
__global__ void carry_scan(const float* __restrict__ L, float* __restrict__ Carry) {
  int i = blockIdx.x * blockDim.x + threadIdx.x;  // 8192
  int b = i >> 11, d = i & (DI - 1);
  float dp = 1.f;
  #pragma unroll
  for (int k = 0; k < CHUNK; ++k) dp *= DECAYF;
  float c = 0.f;
  for (int ch = 0; ch < NCH; ++ch) {
    c = dp * c + L[((size_t)(b * NCH + ch)) * DI + d];
    Carry[((size_t)(b * NCH + ch)) * DI + d] = c;
  }
}

// ---------------- s_C[m][n] = sum_d silu(conv(Xi))[m,d] * W_x[16+n, d] ----------------
// recomputes conv+silu from fp32 Xi (no bf16 anywhere). wave per row.
__global__ __launch_bounds__(256) void sc_gemm(
    const float* __restrict__ Xi, const float* __restrict__ convW, const float* __restrict__ convB,
    const float* __restrict__ Wx, float* __restrict__ sC)
{
  const int m = blockIdx.x * 4 + (threadIdx.x >> 6);
  const int lane = threadIdx.x & 63;
  const int b = m >> 11, t = m & (SLEN - 1);
  const float* rowt = Xi + ((size_t)(b * SLEN + t)) * DI;

  float acc[16];
  #pragma unroll
  for (int n = 0; n < 16; ++n) acc[n] = 0.f;

  #pragma unroll
  for (int it = 0; it < DI / 256; ++it) {
    int d = it * 256 + lane * 4;
    float4 x0 = *(const float4*)&rowt[d];                                        // t
    float4 x1 = (t >= 1) ? *(const float4*)&rowt[d - DI]     : (float4){0,0,0,0}; // t-1
    float4 x2 = (t >= 2) ? *(const float4*)&rowt[d - 2*DI]   : (float4){0,0,0,0}; // t-2
    float4 x3 = (t >= 3) ? *(const float4*)&rowt[d - 3*DI]   : (float4){0,0,0,0}; // t-3
    float xt[4]  = {x0.x, x0.y, x0.z, x0.w};
    float m1[4]  = {x1.x, x1.y, x1.z, x1.w};
    float m2[4]  = {x2.x, x2.y, x2.z, x2.w};
    float m3[4]  = {x3.x, x3.y, x3.z, x3.w};
    float xc[4];
    #pragma unroll
    for (int i = 0; i < 4; ++i) {
      float4 wv = ((const float4*)convW)[d + i];
      float c = convB[d + i] + wv.x * m3[i] + wv.y * m2[i] + wv.z * m1[i] + wv.w * xt[i];
      xc[i] = silu_f(c);
    }
    #pragma unroll
    for (int n = 0; n < 16; ++n) {
      float4 wv = *(const float4*)&Wx[(size_t)(16 + n) * DI + d];
      acc[n] += xc[0] * wv.x + xc[1] * wv.y + xc[2] * wv.z + xc[3] * wv.w;
    }
  }
  #pragma unroll
  for (int n = 0; n < 16; ++n) {
    #pragma unroll
    for (int off = 32; off > 0; off >>= 1) acc[n] += __shfl_xor(acc[n], off);
  }
  if (lane == 0) {
    #pragma unroll
    for (int n = 0; n < 16; ++n) sC[m * 16 + n] = acc[n];
  }
}

// ---------------- Y = (Hl + coef*Carry) * (sC·expBT) * Zs ; 3-split rows [hi|hi|lo] ----------------
__global__ __launch_bounds__(256) void ew_y(
    const float* __restrict__ Hl, const float* __restrict__ Zs,
    const float* __restrict__ sC, const float* __restrict__ expBT,
    const float* __restrict__ Carry, u16* __restrict__ Y)
{
  const int r = threadIdx.x >> 6, lane = threadIdx.x & 63;
  const int m = blockIdx.y * 4 + r;
  const int d0 = blockIdx.x * 512 + lane * 8;
  const int b = m >> 11, t = m & (SLEN - 1);
  const int ch = t >> 6, tl = t & (CHUNK - 1);

  float coef = 0.f;
  if (ch > 0) {
    coef = 1.f;
    for (int j = 0; j <= tl; ++j) coef *= DECAYF;  // 0.95^(tl+1), repeated-multiply like ref
  }

  const float4 sc0 = *(const float4*)&sC[m * 16 + 0];
  const float4 sc1 = *(const float4*)&sC[m * 16 + 4];
  const float4 sc2 = *(const float4*)&sC[m * 16 + 8];
  const float4 sc3 = *(const float4*)&sC[m * 16 + 12];
  const float scv[16] = {sc0.x, sc0.y, sc0.z, sc0.w, sc1.x, sc1.y, sc1.z, sc1.w,
                         sc2.x, sc2.y, sc2.z, sc2.w, sc3.x, sc3.y, sc3.z, sc3.w};

  const size_t ro = (size_t)m * DI + d0;
  float4 h0 = *(const float4*)&Hl[ro],     h1 = *(const float4*)&Hl[ro + 4];
  float4 z0 = *(const float4*)&Zs[ro],     z1 = *(const float4*)&Zs[ro + 4];
  float hv[8] = {h0.x, h0.y, h0.z, h0.w, h1.x, h1.y, h1.z, h1.w};
  float zv[8] = {z0.x, z0.y, z0.z, z0.w, z1.x, z1.y, z1.z, z1.w};
  float ca[8] = {0.f, 0.f, 0.f, 0.f, 0.f, 0.f, 0.f, 0.f};
  if (ch > 0) {
    const size_t co = ((size_t)(b * NCH + ch - 1)) * DI + d0;
    float4 c0 = *(const float4*)&Carry[co];
    float4 c1 = *(const float4*)&Carry[co + 4];
    ca[0] = c0.x; ca[1] = c0.y; ca[2] = c0.z; ca[3] = c0.w;
    ca[4] = c1.x; ca[5] = c1.y; ca[6] = c1.z; ca[7] = c1.w;
  }

  float cp[8] = {0.f, 0.f, 0.f, 0.f, 0.f, 0.f, 0.f, 0.f};
  #pragma unroll
  for (int n = 0; n < 16; ++n) {
    float4 e0 = *(const float4*)&expBT[(size_t)n * DI + d0];
    float4 e1 = *(const float4*)&expBT[(size_t)n * DI + d0 + 4];
    cp[0] += scv[n] * e0.x; cp[1] += scv[n] * e0.y; cp[2] += scv[n] * e0.z; cp[3] += scv[n] * e0.w;
    cp[4] += scv[n] * e1.x; cp[5] += scv[n] * e1.y; cp[6] += scv[n] * e1.z; cp[7] += scv[n] * e1.w;
  }

  float y[8];
  #pragma unroll
  for (int i = 0; i < 8; ++i) y[i] = (hv[i] + coef * ca[i]) * cp[i] * zv[i];
  ushort4 hi0, hi1, lo0, lo1;
  hi0.x = f2bf(y[0]); hi0.y = f2bf(y[1]); hi0.z = f2bf(y[2]); hi0.w = f2bf(y[3]);
  hi1.x = f2bf(y[4]); hi1.y = f2bf(y[5]); hi1.z = f2bf(y[6]); hi1.w = f2bf(y[7]);
  lo0.x = f2bf(y[0] - bf2f(hi0.x)); lo0.y = f2bf(y[1] - bf2f(hi0.y));
  lo0.z = f2bf(y[2] - bf2f(hi0.z)); lo0.w = f2bf(y[3] - bf2f(hi0.w));
  lo1.x = f2bf(y[4] - bf2f(hi1.x)); lo1.y = f2bf(y[5] - bf2f(hi1.y));
  lo1.z = f2bf(y[6] - bf2f(hi1.z)); lo1.w = f2bf(y[7] - bf2f(hi1.w));
  const size_t yo = (size_t)m * (3 * DI) + d0;
  *(ushort4*)&Y[yo] = hi0;
  *(ushort4*)&Y[yo + 4] = hi1;
  *(ushort4*)&Y[yo + DI] = hi0;
  *(ushort4*)&Y[yo + DI + 4] = hi1;
  *(ushort4*)&Y[yo + 2 * DI] = lo0;
  *(ushort4*)&Y[yo + 2 * DI + 4] = lo1;
}

// ---------------- residual + LayerNorm (row = 1024) ----------------
__global__ __launch_bounds__(256) void ln_res(const float* __restrict__ G, const float* __restrict__ x,
                                              const float* __restrict__ lng, const float* __restrict__ lnb,
                                              float* __restrict__ out) {
  const int m = blockIdx.x;
  const int tid = threadIdx.x;
  float4 gv = ((const float4*)(G + (size_t)m * DM))[tid];
  float4 xv = ((const float4*)(x + (size_t)m * DM))[tid];
  float4 rv = {gv.x + xv.x, gv.y + xv.y, gv.z + xv.z, gv.w + xv.w};
  float s = rv.x + rv.y + rv.z + rv.w;
  float s2 = rv.x * rv.x + rv.y * rv.y + rv.z * rv.z + rv.w * rv.w;
  #pragma unroll
  for (int off = 32; off > 0; off >>= 1) {
    s += __shfl_xor(s, off);
    s2 += __shfl_xor(s2, off);
  }
  __shared__ float ps[8];
  const int w = tid >> 6;
  if ((tid & 63) == 0) { ps[w] = s; ps[w + 4] = s2; }
  __syncthreads();
  float S = ps[0] + ps[1] + ps[2] + ps[3];
  float S2 = ps[4] + ps[5] + ps[6] + ps[7];
  float mu = S * (1.f / DM);
  float var = S2 * (1.f / DM) - mu * mu;
  float rs = rsqrtf(var + 1e-5f);
  float4 gg = ((const float4*)lng)[tid];
  float4 bb = ((const float4*)lnb)[tid];
  float4 ov = {(rv.x - mu) * rs * gg.x + bb.x, (rv.y - mu) * rs * gg.y + bb.y,
               (rv.z - mu) * rs * gg.z + bb.z, (rv.w - mu) * rs * gg.w + bb.w};
  ((float4*)(out + (size_t)m * DM))[tid] = ov;
}

extern "C" void kernel_launch(void* const* d_in, const int* in_sizes, int n_in,
                              void* d_out, int out_size, void* d_ws, size_t ws_size,
                              hipStream_t stream) {
  const float* x      = (const float*)d_in[0];
  const float* W_in   = (const float*)d_in[1];
  const float* conv_w = (const float*)d_in[2];
  const float* conv_b = (const float*)d_in[3];
  const float* W_x    = (const float*)d_in[4];
  const float* B_log  = (const float*)d_in[5];
  const float* W_out  = (const float*)d_in[6];
  const float* ln_g   = (const float*)d_in[7];
  const float* ln_b   = (const float*)d_in[8];
  float* out = (float*)d_out;

  char* ws = (char*)d_ws;
  // Region map (byte offsets, peak ~247.2MB):
  //  [0,64)    Xi fp32            -> after sc_gemm: Yp split-bf16 [0,96)
  //  [96,144)  A1 bf16 48MB       -> after gemm1: Hl fp32 [96,160)
  //  [144,168) B1 bf16 24MB       (head overlaid by Hl)
  //  [168,180) W2 bf16 12MB (persistent)
  //  [180,244) Zs fp32 64MB       -> after ew_y: G fp32 [180,212)
  //  [244,245) L ; [245,246) Carry ; [246,*) sC ; [247,*) expBT
  float* Xi  = (float*)(ws + 0);
  u16*   Yp  = (u16*)(ws + 0);
  u16*   A1  = (u16*)(ws + 96 * MB);
  float* Hl  = (float*)(ws + 96 * MB);
  u16*   B1  = (u16*)(ws + 144 * MB);
  u16*   W2  = (u16*)(ws + 168 * MB);
  float* Zs  = (float*)(ws + 180 * MB);
  float* G   = (float*)(ws + 180 * MB);
  float* L     = (float*)(ws + 244 * MB);
  float* Carry = (float*)(ws + 245 * MB);
  float* sC    = (float*)(ws + 246 * MB);
  float* expBT = (float*)(ws + 247 * MB);

  split3_a<<<(MROWS * DM / 4 + 255) / 256, 256, 0, stream>>>(x, A1, DM / 4, MROWS * DM / 4);
  split3_w<<<(2 * DI * DM / 4 + 255) / 256, 256, 0, stream>>>(W_in, B1, DM / 4, 2 * DI * DM / 4);
  split3_w<<<(DM * DI / 4 + 255) / 256, 256, 0, stream>>>(W_out, W2, DI / 4, DM * DI / 4);
  expb_t<<<(NST * DI) / 256, 256, 0, stream>>>(B_log, expBT);

  // GEMM1: [8192 x 4096] = A1[8192 x 3072] * B1[4096 x 3072]^T (fp32-exact via 3-split)
  gemm_bt<1><<<dim3(2 * DI / 128, MROWS / 128), 256, 0, stream>>>(
      A1, B1, MROWS, 2 * DI, 3 * DM, nullptr, Xi, Zs);

  conv_scan<<<dim3(DI / 1024, NCH, BSZ), 256, 0, stream>>>(Xi, conv_w, conv_b, Hl, L);
  carry_scan<<<(BSZ * DI) / 256, 256, 0, stream>>>(L, Carry);
  sc_gemm<<<MROWS / 4, 256, 0, stream>>>(Xi, conv_w, conv_b, W_x, sC);
  ew_y<<<dim3(DI / 512, MROWS / 4), 256, 0, stream>>>(Hl, Zs, sC, expBT, Carry, Yp);

  // GEMM2: [8192 x 1024] = Yp[8192 x 6144] * W2[1024 x 6144]^T (fp32-exact via 3-split)
  gemm_bt<0><<<dim3(DM / 128, MROWS / 128), 256, 0, stream>>>(
      Yp, W2, MROWS, DM, 3 * DI, G, nullptr, nullptr);

  ln_res<<<MROWS, 256, 0, stream>>>(G, x, ln_g, ln_b, out);
}

// Round 5
// 330.354 us; speedup vs baseline: 2.7764x; 2.7764x over previous
//
#include <hip/hip_runtime.h>
#include <hip/hip_bf16.h>
#include <stdint.h>

#define DM   1024
#define DI   2048
#define NST  16
#define BSZ  4
#define SLEN 2048
#define MROWS (BSZ*SLEN)   // 8192
#define CHUNK 32
#define NCH  (SLEN/CHUNK)  // 64
#define DECAYF 0.95f
#define MB (size_t)1048576

typedef unsigned short u16;
typedef _Float16 f16;
typedef __attribute__((ext_vector_type(2))) _Float16 f16x2;
typedef __attribute__((ext_vector_type(4))) _Float16 f16x4;
typedef __attribute__((ext_vector_type(8))) _Float16 f16x8;
typedef __attribute__((ext_vector_type(4))) float f32x4;

__device__ __forceinline__ float silu_f(float v) { return v / (1.f + __expf(-v)); }

__device__ __forceinline__ void gload16(const f16* lds, const f16* g) {
  __builtin_amdgcn_global_load_lds((const __attribute__((address_space(1))) void*)g,
                                   (__attribute__((address_space(3))) void*)lds, 16, 0, 0);
}

// ---------------- fp32 -> fp16 convert (vectorized) ----------------
__global__ void cvt_f16(const float* __restrict__ in, f16* __restrict__ out, int n4) {
  int i = blockIdx.x * blockDim.x + threadIdx.x;
  if (i < n4) {
    float4 v = ((const float4*)in)[i];
    f16x4 o = {(f16)v.x, (f16)v.y, (f16)v.z, (f16)v.w};
    ((f16x4*)out)[i] = o;
  }
}

// ---------------- expB transposed: expBT[n][d] = exp(B_log[d][n]) ----------------
__global__ void expb_t(const float* __restrict__ B_log, float* __restrict__ expBT) {
  int i = blockIdx.x * blockDim.x + threadIdx.x;  // 32768
  int n = i >> 11, d = i & (DI - 1);
  expBT[i] = __expf(B_log[d * NST + n]);
}

// ---------------- fp16 MFMA GEMM: C[m,n] = sum_k A[m,k]*Bt[n,k] ----------------
// MODE 0: Cf[m*N+n] = v (fp32)
// MODE 1: n < DI -> Xi (fp32) ; n >= DI -> Zs = silu(v) (fp16)
template<int MODE>
__global__ __launch_bounds__(256) void gemm_bt(
    const f16* __restrict__ A, const f16* __restrict__ Bt,
    int M, int N, int K,
    float* __restrict__ Cf, float* __restrict__ Xi, f16* __restrict__ Zs)
{
  __shared__ __align__(16) f16 sA[128 * 32];
  __shared__ __align__(16) f16 sB[128 * 32];
  const int tid  = threadIdx.x;
  const int lane = tid & 63;
  const int w    = tid >> 6;
  const int wr   = w >> 1, wc = w & 1;

  // bijective XCD swizzle (nwg % 8 == 0 for both GEMMs)
  const int nwg  = gridDim.x * gridDim.y;
  int wgid = blockIdx.y * gridDim.x + blockIdx.x;
  wgid = (wgid & 7) * (nwg >> 3) + (wgid >> 3);
  const int bx = wgid % gridDim.x;
  const int by = wgid / gridDim.x;

  const int mBase = by * 128;
  const int nBase = bx * 128;
  const int lr = lane & 15;
  const int lu = lane >> 4;   // logical 16B unit (0..3)

  f32x4 acc[4][4];
  #pragma unroll
  for (int m = 0; m < 4; ++m)
    #pragma unroll
    for (int n = 0; n < 4; ++n)
      acc[m][n] = (f32x4){0.f, 0.f, 0.f, 0.f};

  for (int k0 = 0; k0 < K; k0 += 32) {
    #pragma unroll
    for (int j = 0; j < 2; ++j) {
      int c = j * 256 + tid;
      int row = c >> 2, p = c & 3;
      int src_u = p ^ (row & 3);  // pre-swizzled source so LDS holds swizzled layout
      gload16(&sA[c * 8], A + (size_t)(mBase + row) * K + k0 + src_u * 8);
      gload16(&sB[c * 8], Bt + (size_t)(nBase + row) * K + k0 + src_u * 8);
    }
    __syncthreads();
    f16x8 af[4], bfr[4];
    #pragma unroll
    for (int m = 0; m < 4; ++m) {
      int ra = wr * 64 + m * 16 + lr;
      af[m] = *(const f16x8*)&sA[ra * 32 + (lu ^ (ra & 3)) * 8];
    }
    #pragma unroll
    for (int n = 0; n < 4; ++n) {
      int rb = wc * 64 + n * 16 + lr;
      bfr[n] = *(const f16x8*)&sB[rb * 32 + (lu ^ (rb & 3)) * 8];
    }
    #pragma unroll
    for (int m = 0; m < 4; ++m)
      #pragma unroll
      for (int n = 0; n < 4; ++n)
        acc[m][n] = __builtin_amdgcn_mfma_f32_16x16x32_f16(af[m], bfr[n], acc[m][n], 0, 0, 0);
    __syncthreads();
  }

  const int rq = (lane >> 4) * 4;
  #pragma unroll
  for (int m = 0; m < 4; ++m) {
    #pragma unroll
    for (int n = 0; n < 4; ++n) {
      int col = nBase + wc * 64 + n * 16 + lr;
      #pragma unroll
      for (int r = 0; r < 4; ++r) {
        int row = mBase + wr * 64 + m * 16 + rq + r;
        float v = acc[m][n][r];
        if (MODE == 0) {
          Cf[(size_t)row * N + col] = v;
        } else {
          if (col < DI) Xi[(size_t)row * DI + col] = v;
          else          Zs[(size_t)row * DI + (col - DI)] = (f16)silu_f(v);
        }
      }
    }
  }
}

// ---------------- depthwise causal conv (w=4) + SiLU + chunked local scan ----------------
// grid: (DI/512, NCH, BSZ), block 256, 2 d per thread. Xi fp32 in; Xc,Hl fp16 out.
__global__ __launch_bounds__(256) void conv_scan(
    const float* __restrict__ Xi, const float* __restrict__ convW, const float* __restrict__ convB,
    f16* __restrict__ Xc, f16* __restrict__ Hl, float* __restrict__ L)
{
  const int tid = threadIdx.x;
  const int d0 = (blockIdx.x * 256 + tid) * 2;
  const int ch = blockIdx.y;
  const int b  = blockIdx.z;
  const int t0 = ch * CHUNK;

  float w0[2], w1[2], w2[2], w3[2], cb[2];
  #pragma unroll
  for (int i = 0; i < 2; ++i) {
    float4 wv = ((const float4*)convW)[d0 + i];
    w0[i] = wv.x; w1[i] = wv.y; w2[i] = wv.z; w3[i] = wv.w;
    cb[i] = convB[d0 + i];
  }

  auto loadrow = [&](int t, float* dst) {
    if (t < 0) { dst[0] = dst[1] = 0.f; return; }
    float2 v = *(const float2*)&Xi[((size_t)(b * SLEN + t)) * DI + d0];
    dst[0] = v.x; dst[1] = v.y;
  };

  float xm3[2], xm2[2], xm1[2];
  loadrow(t0 - 3, xm3); loadrow(t0 - 2, xm2); loadrow(t0 - 1, xm1);

  float h[2] = {0.f, 0.f};
  for (int t = 0; t < CHUNK; ++t) {
    const size_t ro = ((size_t)(b * SLEN + t0 + t)) * DI + d0;
    float2 xv = *(const float2*)&Xi[ro];
    float xt[2] = {xv.x, xv.y};
    float xc[2];
    #pragma unroll
    for (int i = 0; i < 2; ++i) {
      float c = cb[i] + w0[i]*xm3[i] + w1[i]*xm2[i] + w2[i]*xm1[i] + w3[i]*xt[i];
      xc[i] = silu_f(c);
      h[i] = DECAYF * h[i] + xc[i];
    }
    f16x2 xco = {(f16)xc[0], (f16)xc[1]};
    f16x2 hho = {(f16)h[0], (f16)h[1]};
    *(f16x2*)&Xc[ro] = xco;
    *(f16x2*)&Hl[ro] = hho;
    #pragma unroll
    for (int i = 0; i < 2; ++i) { xm3[i] = xm2[i]; xm2[i] = xm1[i]; xm1[i] = xt[i]; }
  }
  float2 lo = {h[0], h[1]};
  *(float2*)&L[((size_t)(b * NCH + ch)) * DI + d0] = lo;
}

// ---------------- sequential chunk-carry ----------------
__global__ void carry_scan(const float* __restrict__ L, float* __restrict__ Carry) {
  int i = blockIdx.x * blockDim.x + threadIdx.x;  // 8192
  int b = i >> 11, d = i & (DI - 1);
  float dp = 1.f;
  #pragma unroll
  for (int k = 0; k < CHUNK; ++k) dp *= DECAYF;
  float c = 0.f;
  for (int ch = 0; ch < NCH; ++ch) {
    c = dp * c + L[((size_t)(b * NCH + ch)) * DI + d];
    Carry[((size_t)(b * NCH + ch)) * DI + d] = c;
  }
}

// ---------------- s_C[m][n] = sum_d Xc[m,d] * W_x[16+n, d]  (wave per row) ----------------
__global__ __launch_bounds__(256) void sc_gemm(const f16* __restrict__ Xc, const float* __restrict__ Wx,
                                               float* __restrict__ sC) {
  const int m = blockIdx.x * 4 + (threadIdx.x >> 6);
  const int lane = threadIdx.x & 63;
  float acc[16];
  #pragma unroll
  for (int n = 0; n < 16; ++n) acc[n] = 0.f;
  #pragma unroll
  for (int it = 0; it < DI / 256; ++it) {
    int d = it * 256 + lane * 4;
    f16x4 xv = *(const f16x4*)&Xc[(size_t)m * DI + d];
    float x0 = (float)xv.x, x1 = (float)xv.y, x2 = (float)xv.z, x3 = (float)xv.w;
    #pragma unroll
    for (int n = 0; n < 16; ++n) {
      float4 wv = *(const float4*)&Wx[(size_t)(16 + n) * DI + d];
      acc[n] += x0 * wv.x + x1 * wv.y + x2 * wv.z + x3 * wv.w;
    }
  }
  #pragma unroll
  for (int n = 0; n < 16; ++n) {
    #pragma unroll
    for (int off = 32; off > 0; off >>= 1) acc[n] += __shfl_xor(acc[n], off);
  }
  if (lane == 0) {
    #pragma unroll
    for (int n = 0; n < 16; ++n) sC[m * 16 + n] = acc[n];
  }
}

// ---------------- Y = (Hl + coef*Carry) * (sC·expBT) * Zs ; fp16 out ----------------
// grid: (DI/512, MROWS/4), block 256 (4 rows x 64 lanes x 8 d)
__global__ __launch_bounds__(256) void ew_y(
    const f16* __restrict__ Hl, const f16* __restrict__ Zs,
    const float* __restrict__ sC, const float* __restrict__ expBT,
    const float* __restrict__ Carry, f16* __restrict__ Y)
{
  const int r = threadIdx.x >> 6, lane = threadIdx.x & 63;
  const int m = blockIdx.y * 4 + r;
  const int d0 = blockIdx.x * 512 + lane * 8;
  const int b = m >> 11, t = m & (SLEN - 1);
  const int ch = t / CHUNK, tl = t & (CHUNK - 1);

  float coef = 0.f;
  if (ch > 0) {
    coef = 1.f;
    for (int j = 0; j <= tl; ++j) coef *= DECAYF;  // 0.95^(tl+1), repeated-mul like ref
  }

  const float4 sc0 = *(const float4*)&sC[m * 16 + 0];
  const float4 sc1 = *(const float4*)&sC[m * 16 + 4];
  const float4 sc2 = *(const float4*)&sC[m * 16 + 8];
  const float4 sc3 = *(const float4*)&sC[m * 16 + 12];
  const float scv[16] = {sc0.x, sc0.y, sc0.z, sc0.w, sc1.x, sc1.y, sc1.z, sc1.w,
                         sc2.x, sc2.y, sc2.z, sc2.w, sc3.x, sc3.y, sc3.z, sc3.w};

  const size_t ro = (size_t)m * DI + d0;
  f16x8 hvv = *(const f16x8*)&Hl[ro];
  f16x8 zvv = *(const f16x8*)&Zs[ro];
  float hv[8], zv[8], ca[8];
  #pragma unroll
  for (int i = 0; i < 8; ++i) { hv[i] = (float)hvv[i]; zv[i] = (float)zvv[i]; ca[i] = 0.f; }
  if (ch > 0) {
    const size_t co = ((size_t)(b * NCH + ch - 1)) * DI + d0;
    float4 c0 = *(const float4*)&Carry[co];
    float4 c1 = *(const float4*)&Carry[co + 4];
    ca[0] = c0.x; ca[1] = c0.y; ca[2] = c0.z; ca[3] = c0.w;
    ca[4] = c1.x; ca[5] = c1.y; ca[6] = c1.z; ca[7] = c1.w;
  }

  float cp[8] = {0.f, 0.f, 0.f, 0.f, 0.f, 0.f, 0.f, 0.f};
  #pragma unroll
  for (int n = 0; n < 16; ++n) {
    float4 e0 = *(const float4*)&expBT[(size_t)n * DI + d0];
    float4 e1 = *(const float4*)&expBT[(size_t)n * DI + d0 + 4];
    cp[0] += scv[n] * e0.x; cp[1] += scv[n] * e0.y; cp[2] += scv[n] * e0.z; cp[3] += scv[n] * e0.w;
    cp[4] += scv[n] * e1.x; cp[5] += scv[n] * e1.y; cp[6] += scv[n] * e1.z; cp[7] += scv[n] * e1.w;
  }

  f16x8 o;
  #pragma unroll
  for (int i = 0; i < 8; ++i) {
    float y = (hv[i] + coef * ca[i]) * cp[i] * zv[i];
    o[i] = (f16)y;
  }
  *(f16x8*)&Y[ro] = o;
}

// ---------------- residual + LayerNorm (row = 1024) ----------------
__global__ __launch_bounds__(256) void ln_res(const float* __restrict__ G, const float* __restrict__ x,
                                              const float* __restrict__ lng, const float* __restrict__ lnb,
                                              float* __restrict__ out) {
  const int m = blockIdx.x;
  const int tid = threadIdx.x;
  float4 gv = ((const float4*)(G + (size_t)m * DM))[tid];
  float4 xv = ((const float4*)(x + (size_t)m * DM))[tid];
  float4 rv = {gv.x + xv.x, gv.y + xv.y, gv.z + xv.z, gv.w + xv.w};
  float s = rv.x + rv.y + rv.z + rv.w;
  float s2 = rv.x * rv.x + rv.y * rv.y + rv.z * rv.z + rv.w * rv.w;
  #pragma unroll
  for (int off = 32; off > 0; off >>= 1) {
    s += __shfl_xor(s, off);
    s2 += __shfl_xor(s2, off);
  }
  __shared__ float ps[8];
  const int w = tid >> 6;
  if ((tid & 63) == 0) { ps[w] = s; ps[w + 4] = s2; }
  __syncthreads();
  float S = ps[0] + ps[1] + ps[2] + ps[3];
  float S2 = ps[4] + ps[5] + ps[6] + ps[7];
  float mu = S * (1.f / DM);
  float var = S2 * (1.f / DM) - mu * mu;
  float rs = rsqrtf(var + 1e-5f);
  float4 gg = ((const float4*)lng)[tid];
  float4 bb = ((const float4*)lnb)[tid];
  float4 ov = {(rv.x - mu) * rs * gg.x + bb.x, (rv.y - mu) * rs * gg.y + bb.y,
               (rv.z - mu) * rs * gg.z + bb.z, (rv.w - mu) * rs * gg.w + bb.w};
  ((float4*)(out + (size_t)m * DM))[tid] = ov;
}

extern "C" void kernel_launch(void* const* d_in, const int* in_sizes, int n_in,
                              void* d_out, int out_size, void* d_ws, size_t ws_size,
                              hipStream_t stream) {
  const float* x      = (const float*)d_in[0];
  const float* W_in   = (const float*)d_in[1];
  const float* conv_w = (const float*)d_in[2];
  const float* conv_b = (const float*)d_in[3];
  const float* W_x    = (const float*)d_in[4];
  const float* B_log  = (const float*)d_in[5];
  const float* W_out  = (const float*)d_in[6];
  const float* ln_g   = (const float*)d_in[7];
  const float* ln_b   = (const float*)d_in[8];
  float* out = (float*)d_out;

  char* ws = (char*)d_ws;
  // Region map (MB offsets, peak ~194MB):
  //  [0,64)    Xi fp32   -> dead after conv_scan -> Yp f16 [0,32), G fp32 [32,64)
  //  [64,96)   Zs f16
  //  [96,128)  Xc f16
  //  [128,160) Hl f16
  //  [160,176) A1 f16 (x)
  //  [176,184) B1 f16 (W_in)
  //  [184,188) W2 f16 (W_out)
  //  [188,190) L ; [190,192) Carry ; [192,..) sC ; [193,..) expBT
  float* Xi  = (float*)(ws + 0);
  f16*   Yp  = (f16*)(ws + 0);
  float* G   = (float*)(ws + 32 * MB);
  f16*   Zs  = (f16*)(ws + 64 * MB);
  f16*   Xc  = (f16*)(ws + 96 * MB);
  f16*   Hl  = (f16*)(ws + 128 * MB);
  f16*   A1  = (f16*)(ws + 160 * MB);
  f16*   B1  = (f16*)(ws + 176 * MB);
  f16*   W2  = (f16*)(ws + 184 * MB);
  float* L     = (float*)(ws + 188 * MB);
  float* Carry = (float*)(ws + 190 * MB);
  float* sC    = (float*)(ws + 192 * MB);
  float* expBT = (float*)(ws + 193 * MB);

  cvt_f16<<<(MROWS * DM / 4 + 255) / 256, 256, 0, stream>>>(x, A1, MROWS * DM / 4);
  cvt_f16<<<(2 * DI * DM / 4 + 255) / 256, 256, 0, stream>>>(W_in, B1, 2 * DI * DM / 4);
  cvt_f16<<<(DM * DI / 4 + 255) / 256, 256, 0, stream>>>(W_out, W2, DM * DI / 4);
  expb_t<<<(NST * DI) / 256, 256, 0, stream>>>(B_log, expBT);

  // GEMM1: [8192 x 4096] = A1[8192 x 1024] * B1[4096 x 1024]^T
  gemm_bt<1><<<dim3(2 * DI / 128, MROWS / 128), 256, 0, stream>>>(
      A1, B1, MROWS, 2 * DI, DM, nullptr, Xi, Zs);

  conv_scan<<<dim3(DI / 512, NCH, BSZ), 256, 0, stream>>>(Xi, conv_w, conv_b, Xc, Hl, L);
  carry_scan<<<(BSZ * DI) / 256, 256, 0, stream>>>(L, Carry);
  sc_gemm<<<MROWS / 4, 256, 0, stream>>>(Xc, W_x, sC);
  ew_y<<<dim3(DI / 512, MROWS / 4), 256, 0, stream>>>(Hl, Zs, sC, expBT, Carry, Yp);

  // GEMM2: [8192 x 1024] = Yp[8192 x 2048] * W2[1024 x 2048]^T
  gemm_bt<0><<<dim3(DM / 128, MROWS / 128), 256, 0, stream>>>(
      Yp, W2, MROWS, DM, DI, G, nullptr, nullptr);

  ln_res<<<MROWS, 256, 0, stream>>>(G, x, ln_g, ln_b, out);
}

// Round 6
// 268.465 us; speedup vs baseline: 3.4164x; 1.2305x over previous
//
#include <hip/hip_runtime.h>
#include <hip/hip_bf16.h>
#include <stdint.h>

#define DM   1024
#define DI   2048
#define NST  16
#define BSZ  4
#define SLEN 2048
#define MROWS (BSZ*SLEN)   // 8192
#define CHUNK 32
#define NCH  (SLEN/CHUNK)  // 64
#define DECAYF 0.95f
#define MB (size_t)1048576

typedef _Float16 f16;
typedef __attribute__((ext_vector_type(2))) _Float16 f16x2;
typedef __attribute__((ext_vector_type(4))) _Float16 f16x4;
typedef __attribute__((ext_vector_type(8))) _Float16 f16x8;
typedef __attribute__((ext_vector_type(4))) float f32x4;

__device__ __forceinline__ float silu_f(float v) { return v / (1.f + __expf(-v)); }

__device__ __forceinline__ void gload16(const f16* lds, const f16* g) {
  __builtin_amdgcn_global_load_lds((const __attribute__((address_space(1))) void*)g,
                                   (__attribute__((address_space(3))) void*)lds, 16, 0, 0);
}

// ---------------- fused fp32 -> fp16 converts: x -> A1, W_in -> B1, W_out -> W2 ----------------
#define NX4  (MROWS * DM / 4)          // 2,097,152
#define NWI4 (2 * DI * DM / 4)         // 1,048,576
#define NWO4 (DM * DI / 4)             // 524,288
__global__ __launch_bounds__(256) void cvt_all(
    const float* __restrict__ x, const float* __restrict__ wi, const float* __restrict__ wo,
    f16* __restrict__ A1, f16* __restrict__ B1, f16* __restrict__ W2)
{
  int i = blockIdx.x * 256 + threadIdx.x;
  const float* src; f16* dst; int j;
  if (i < NX4)              { src = x;  dst = A1; j = i; }
  else if (i < NX4 + NWI4)  { src = wi; dst = B1; j = i - NX4; }
  else                      { src = wo; dst = W2; j = i - NX4 - NWI4; }
  float4 v = ((const float4*)src)[j];
  f16x4 o = {(f16)v.x, (f16)v.y, (f16)v.z, (f16)v.w};
  ((f16x4*)dst)[j] = o;
}

// ---------------- expB transposed: expBT[n][d] = exp(B_log[d][n]) ----------------
__global__ void expb_t(const float* __restrict__ B_log, float* __restrict__ expBT) {
  int i = blockIdx.x * blockDim.x + threadIdx.x;  // 32768
  int n = i >> 11, d = i & (DI - 1);
  expBT[i] = __expf(B_log[d * NST + n]);
}

// ---------------- fp16 MFMA GEMM, BK=64, XOR-swizzled LDS, LDS-staged f16 epilogue ----------
// MODE 1: cols < DI -> O0 = Xi (f16), cols >= DI -> O1 = Z raw (f16). MODE 0: O0 = G (f16).
template<int MODE>
__global__ __launch_bounds__(256) void gemm_bt(
    const f16* __restrict__ A, const f16* __restrict__ Bt,
    int K, f16* __restrict__ O0, f16* __restrict__ O1)
{
  __shared__ __align__(16) f16 sA[128 * 64];
  __shared__ __align__(16) f16 sB[128 * 64];
  const int tid  = threadIdx.x;
  const int lane = tid & 63;
  const int w    = tid >> 6;
  const int wr   = w >> 1, wc = w & 1;

  // bijective XCD swizzle (nwg % 8 == 0 for both GEMMs)
  const int nwg  = gridDim.x * gridDim.y;
  int wgid = blockIdx.y * gridDim.x + blockIdx.x;
  wgid = (wgid & 7) * (nwg >> 3) + (wgid >> 3);
  const int bx = wgid % gridDim.x;
  const int by = wgid / gridDim.x;

  const int mBase = by * 128;
  const int nBase = bx * 128;
  const int lr = lane & 15;
  const int lu = lane >> 4;   // k-unit (8 f16) within 32-k window

  f32x4 acc[4][4];
  #pragma unroll
  for (int m = 0; m < 4; ++m)
    #pragma unroll
    for (int n = 0; n < 4; ++n)
      acc[m][n] = (f32x4){0.f, 0.f, 0.f, 0.f};

  // ds_read offsets (f16 units), loop-invariant
  int offA[4][2], offB[4][2];
  #pragma unroll
  for (int m = 0; m < 4; ++m) {
    int ra = wr * 64 + m * 16 + lr;
    int rb = wc * 64 + m * 16 + lr;
    #pragma unroll
    for (int kk = 0; kk < 2; ++kk) {
      offA[m][kk] = ra * 64 + ((kk * 4 + lu) ^ (ra & 7)) * 8;
      offB[m][kk] = rb * 64 + ((kk * 4 + lu) ^ (rb & 7)) * 8;
    }
  }

  for (int k0 = 0; k0 < K; k0 += 64) {
    #pragma unroll
    for (int j = 0; j < 4; ++j) {
      int c = j * 256 + tid;          // chunk of 8 f16; dest stays base + lane*16B
      int row = c >> 3, p = c & 7;
      int su = p ^ (row & 7);         // pre-swizzled source -> swizzled LDS layout
      gload16(&sA[c * 8], A  + (size_t)(mBase + row) * K + k0 + su * 8);
      gload16(&sB[c * 8], Bt + (size_t)(nBase + row) * K + k0 + su * 8);
    }
    __syncthreads();
    #pragma unroll
    for (int kk = 0; kk < 2; ++kk) {
      f16x8 af[4], bf[4];
      #pragma unroll
      for (int m = 0; m < 4; ++m) af[m] = *(const f16x8*)&sA[offA[m][kk]];
      #pragma unroll
      for (int n = 0; n < 4; ++n) bf[n] = *(const f16x8*)&sB[offB[n][kk]];
      #pragma unroll
      for (int m = 0; m < 4; ++m)
        #pragma unroll
        for (int n = 0; n < 4; ++n)
          acc[m][n] = __builtin_amdgcn_mfma_f32_16x16x32_f16(af[m], bf[n], acc[m][n], 0, 0, 0);
    }
    __syncthreads();
  }

  // epilogue: stage 32x128 f16 quadrants in LDS, write coalesced f16x8
  const int rq = (lane >> 4) * 4;
  f16* sOut = sA;
  const bool isZ = (MODE == 1) && (nBase >= DI);
  f16* dst = (MODE == 0) ? O0 : (isZ ? O1 : O0);
  const int ncols = (MODE == 0) ? DM : DI;
  const int cb = isZ ? (nBase - DI) : nBase;
  #pragma unroll
  for (int m = 0; m < 4; ++m) {
    #pragma unroll
    for (int n = 0; n < 4; ++n)
      #pragma unroll
      for (int r = 0; r < 4; ++r)
        sOut[(wr * 16 + rq + r) * 128 + wc * 64 + n * 16 + lr] = (f16)acc[m][n][r];
    __syncthreads();
    #pragma unroll
    for (int q = 0; q < 2; ++q) {
      int cidx = q * 256 + tid;
      int orow = cidx >> 4;
      int ocol = (cidx & 15) * 8;
      int grow = mBase + (orow >> 4) * 64 + m * 16 + (orow & 15);
      f16x8 v = *(const f16x8*)&sOut[orow * 128 + ocol];
      *(f16x8*)&dst[(size_t)grow * ncols + cb + ocol] = v;
    }
    __syncthreads();
  }
}

// ---------------- depthwise causal conv (w=4) + SiLU + chunked local scan ----------------
// grid: (DI/512, NCH, BSZ), block 256, 2 d per thread. Xi f16 in; Xc,Hl f16 out.
__global__ __launch_bounds__(256) void conv_scan(
    const f16* __restrict__ Xi, const float* __restrict__ convW, const float* __restrict__ convB,
    f16* __restrict__ Xc, f16* __restrict__ Hl, float* __restrict__ L)
{
  const int tid = threadIdx.x;
  const int d0 = (blockIdx.x * 256 + tid) * 2;
  const int ch = blockIdx.y;
  const int b  = blockIdx.z;
  const int t0 = ch * CHUNK;

  float w0[2], w1[2], w2[2], w3[2], cb[2];
  #pragma unroll
  for (int i = 0; i < 2; ++i) {
    float4 wv = ((const float4*)convW)[d0 + i];
    w0[i] = wv.x; w1[i] = wv.y; w2[i] = wv.z; w3[i] = wv.w;
    cb[i] = convB[d0 + i];
  }

  auto loadrow = [&](int t, float* dst) {
    if (t < 0) { dst[0] = dst[1] = 0.f; return; }
    f16x2 v = *(const f16x2*)&Xi[((size_t)(b * SLEN + t)) * DI + d0];
    dst[0] = (float)v.x; dst[1] = (float)v.y;
  };

  float xm3[2], xm2[2], xm1[2];
  loadrow(t0 - 3, xm3); loadrow(t0 - 2, xm2); loadrow(t0 - 1, xm1);

  float h[2] = {0.f, 0.f};
  for (int t = 0; t < CHUNK; ++t) {
    const size_t ro = ((size_t)(b * SLEN + t0 + t)) * DI + d0;
    f16x2 xv = *(const f16x2*)&Xi[ro];
    float xt[2] = {(float)xv.x, (float)xv.y};
    float xc[2];
    #pragma unroll
    for (int i = 0; i < 2; ++i) {
      float c = cb[i] + w0[i]*xm3[i] + w1[i]*xm2[i] + w2[i]*xm1[i] + w3[i]*xt[i];
      xc[i] = silu_f(c);
      h[i] = DECAYF * h[i] + xc[i];
    }
    f16x2 xco = {(f16)xc[0], (f16)xc[1]};
    f16x2 hho = {(f16)h[0], (f16)h[1]};
    *(f16x2*)&Xc[ro] = xco;
    *(f16x2*)&Hl[ro] = hho;
    #pragma unroll
    for (int i = 0; i < 2; ++i) { xm3[i] = xm2[i]; xm2[i] = xm1[i]; xm1[i] = xt[i]; }
  }
  float2 lo = {h[0], h[1]};
  *(float2*)&L[((size_t)(b * NCH + ch)) * DI + d0] = lo;
}

// ---------------- sequential chunk-carry (8-wide batched loads to hide latency) ----------------
__global__ void carry_scan(const float* __restrict__ L, float* __restrict__ Carry) {
  int i = blockIdx.x * blockDim.x + threadIdx.x;  // 8192
  int b = i >> 11, d = i & (DI - 1);
  float dp = 1.f;
  #pragma unroll
  for (int k = 0; k < CHUNK; ++k) dp *= DECAYF;
  float c = 0.f;
  for (int ch0 = 0; ch0 < NCH; ch0 += 8) {
    float lv[8];
    #pragma unroll
    for (int k = 0; k < 8; ++k)
      lv[k] = L[((size_t)(b * NCH + ch0 + k)) * DI + d];
    #pragma unroll
    for (int k = 0; k < 8; ++k) {
      c = dp * c + lv[k];
      Carry[((size_t)(b * NCH + ch0 + k)) * DI + d] = c;
    }
  }
}

// ---------------- s_C[m][n] = sum_d Xc[m,d] * W_x[16+n, d]  (wave per row) ----------------
__global__ __launch_bounds__(256) void sc_gemm(const f16* __restrict__ Xc, const float* __restrict__ Wx,
                                               float* __restrict__ sC) {
  const int m = blockIdx.x * 4 + (threadIdx.x >> 6);
  const int lane = threadIdx.x & 63;
  float acc[16];
  #pragma unroll
  for (int n = 0; n < 16; ++n) acc[n] = 0.f;
  #pragma unroll
  for (int it = 0; it < DI / 256; ++it) {
    int d = it * 256 + lane * 4;
    f16x4 xv = *(const f16x4*)&Xc[(size_t)m * DI + d];
    float x0 = (float)xv.x, x1 = (float)xv.y, x2 = (float)xv.z, x3 = (float)xv.w;
    #pragma unroll
    for (int n = 0; n < 16; ++n) {
      float4 wv = *(const float4*)&Wx[(size_t)(16 + n) * DI + d];
      acc[n] += x0 * wv.x + x1 * wv.y + x2 * wv.z + x3 * wv.w;
    }
  }
  #pragma unroll
  for (int n = 0; n < 16; ++n) {
    #pragma unroll
    for (int off = 32; off > 0; off >>= 1) acc[n] += __shfl_xor(acc[n], off);
  }
  if (lane == 0) {
    #pragma unroll
    for (int n = 0; n < 16; ++n) sC[m * 16 + n] = acc[n];
  }
}

// ---------------- Y = (Hl + coef*Carry) * (sC·expBT) * silu(Z) ; f16 out ----------------
__global__ __launch_bounds__(256) void ew_y(
    const f16* __restrict__ Hl, const f16* __restrict__ Zs,
    const float* __restrict__ sC, const float* __restrict__ expBT,
    const float* __restrict__ Carry, f16* __restrict__ Y)
{
  const int r = threadIdx.x >> 6, lane = threadIdx.x & 63;
  const int m = blockIdx.y * 4 + r;
  const int d0 = blockIdx.x * 512 + lane * 8;
  const int b = m >> 11, t = m & (SLEN - 1);
  const int ch = t / CHUNK, tl = t & (CHUNK - 1);

  float coef = 0.f;
  if (ch > 0) {
    coef = 1.f;
    for (int j = 0; j <= tl; ++j) coef *= DECAYF;  // 0.95^(tl+1), repeated-mul like ref
  }

  const float4 sc0 = *(const float4*)&sC[m * 16 + 0];
  const float4 sc1 = *(const float4*)&sC[m * 16 + 4];
  const float4 sc2 = *(const float4*)&sC[m * 16 + 8];
  const float4 sc3 = *(const float4*)&sC[m * 16 + 12];
  const float scv[16] = {sc0.x, sc0.y, sc0.z, sc0.w, sc1.x, sc1.y, sc1.z, sc1.w,
                         sc2.x, sc2.y, sc2.z, sc2.w, sc3.x, sc3.y, sc3.z, sc3.w};

  const size_t ro = (size_t)m * DI + d0;
  f16x8 hvv = *(const f16x8*)&Hl[ro];
  f16x8 zvv = *(const f16x8*)&Zs[ro];
  float hv[8], zv[8], ca[8];
  #pragma unroll
  for (int i = 0; i < 8; ++i) {
    hv[i] = (float)hvv[i];
    zv[i] = silu_f((float)zvv[i]);
    ca[i] = 0.f;
  }
  if (ch > 0) {
    const size_t co = ((size_t)(b * NCH + ch - 1)) * DI + d0;
    float4 c0 = *(const float4*)&Carry[co];
    float4 c1 = *(const float4*)&Carry[co + 4];
    ca[0] = c0.x; ca[1] = c0.y; ca[2] = c0.z; ca[3] = c0.w;
    ca[4] = c1.x; ca[5] = c1.y; ca[6] = c1.z; ca[7] = c1.w;
  }

  float cp[8] = {0.f, 0.f, 0.f, 0.f, 0.f, 0.f, 0.f, 0.f};
  #pragma unroll
  for (int n = 0; n < 16; ++n) {
    float4 e0 = *(const float4*)&expBT[(size_t)n * DI + d0];
    float4 e1 = *(const float4*)&expBT[(size_t)n * DI + d0 + 4];
    cp[0] += scv[n] * e0.x; cp[1] += scv[n] * e0.y; cp[2] += scv[n] * e0.z; cp[3] += scv[n] * e0.w;
    cp[4] += scv[n] * e1.x; cp[5] += scv[n] * e1.y; cp[6] += scv[n] * e1.z; cp[7] += scv[n] * e1.w;
  }

  f16x8 o;
  #pragma unroll
  for (int i = 0; i < 8; ++i) {
    float y = (hv[i] + coef * ca[i]) * cp[i] * zv[i];
    o[i] = (f16)y;
  }
  *(f16x8*)&Y[ro] = o;
}

// ---------------- residual + LayerNorm (row = 1024), G is f16 ----------------
__global__ __launch_bounds__(256) void ln_res(const f16* __restrict__ G, const float* __restrict__ x,
                                              const float* __restrict__ lng, const float* __restrict__ lnb,
                                              float* __restrict__ out) {
  const int m = blockIdx.x;
  const int tid = threadIdx.x;
  f16x4 gv4 = ((const f16x4*)(G + (size_t)m * DM))[tid];
  float4 xv = ((const float4*)(x + (size_t)m * DM))[tid];
  float4 rv = {(float)gv4.x + xv.x, (float)gv4.y + xv.y, (float)gv4.z + xv.z, (float)gv4.w + xv.w};
  float s = rv.x + rv.y + rv.z + rv.w;
  float s2 = rv.x * rv.x + rv.y * rv.y + rv.z * rv.z + rv.w * rv.w;
  #pragma unroll
  for (int off = 32; off > 0; off >>= 1) {
    s += __shfl_xor(s, off);
    s2 += __shfl_xor(s2, off);
  }
  __shared__ float ps[8];
  const int w = tid >> 6;
  if ((tid & 63) == 0) { ps[w] = s; ps[w + 4] = s2; }
  __syncthreads();
  float S = ps[0] + ps[1] + ps[2] + ps[3];
  float S2 = ps[4] + ps[5] + ps[6] + ps[7];
  float mu = S * (1.f / DM);
  float var = S2 * (1.f / DM) - mu * mu;
  float rs = rsqrtf(var + 1e-5f);
  float4 gg = ((const float4*)lng)[tid];
  float4 bb = ((const float4*)lnb)[tid];
  float4 ov = {(rv.x - mu) * rs * gg.x + bb.x, (rv.y - mu) * rs * gg.y + bb.y,
               (rv.z - mu) * rs * gg.z + bb.z, (rv.w - mu) * rs * gg.w + bb.w};
  ((float4*)(out + (size_t)m * DM))[tid] = ov;
}

extern "C" void kernel_launch(void* const* d_in, const int* in_sizes, int n_in,
                              void* d_out, int out_size, void* d_ws, size_t ws_size,
                              hipStream_t stream) {
  const float* x      = (const float*)d_in[0];
  const float* W_in   = (const float*)d_in[1];
  const float* conv_w = (const float*)d_in[2];
  const float* conv_b = (const float*)d_in[3];
  const float* W_x    = (const float*)d_in[4];
  const float* B_log  = (const float*)d_in[5];
  const float* W_out  = (const float*)d_in[6];
  const float* ln_g   = (const float*)d_in[7];
  const float* ln_b   = (const float*)d_in[8];
  float* out = (float*)d_out;

  char* ws = (char*)d_ws;
  // Region map (MB offsets, peak ~178MB):
  //  [0,32)    Xi f16  -> dead after sc-feed (conv) -> Yp f16 [0,32)
  //  [32,64)   Zs f16 (raw z)
  //  [64,96)   Xc f16
  //  [96,128)  Hl f16
  //  [128,144) A1 f16 (x)
  //  [144,152) B1 f16 (W_in)
  //  [152,156) W2 f16 (W_out)
  //  [156,172) G f16
  //  [172,174) L ; [174,176) Carry ; [176,177) sC ; [177,..) expBT
  f16*   Xi  = (f16*)(ws + 0);
  f16*   Yp  = (f16*)(ws + 0);
  f16*   Zs  = (f16*)(ws + 32 * MB);
  f16*   Xc  = (f16*)(ws + 64 * MB);
  f16*   Hl  = (f16*)(ws + 96 * MB);
  f16*   A1  = (f16*)(ws + 128 * MB);
  f16*   B1  = (f16*)(ws + 144 * MB);
  f16*   W2  = (f16*)(ws + 152 * MB);
  f16*   G   = (f16*)(ws + 156 * MB);
  float* L     = (float*)(ws + 172 * MB);
  float* Carry = (float*)(ws + 174 * MB);
  float* sC    = (float*)(ws + 176 * MB);
  float* expBT = (float*)(ws + 177 * MB);

  cvt_all<<<(NX4 + NWI4 + NWO4) / 256, 256, 0, stream>>>(x, W_in, W_out, A1, B1, W2);
  expb_t<<<(NST * DI) / 256, 256, 0, stream>>>(B_log, expBT);

  // GEMM1: [8192 x 4096] = A1[8192 x 1024] * B1[4096 x 1024]^T -> Xi f16, Z raw f16
  gemm_bt<1><<<dim3(2 * DI / 128, MROWS / 128), 256, 0, stream>>>(A1, B1, DM, Xi, Zs);

  conv_scan<<<dim3(DI / 512, NCH, BSZ), 256, 0, stream>>>(Xi, conv_w, conv_b, Xc, Hl, L);
  carry_scan<<<(BSZ * DI) / 256, 256, 0, stream>>>(L, Carry);
  sc_gemm<<<MROWS / 4, 256, 0, stream>>>(Xc, W_x, sC);
  ew_y<<<dim3(DI / 512, MROWS / 4), 256, 0, stream>>>(Hl, Zs, sC, expBT, Carry, Yp);

  // GEMM2: [8192 x 1024] = Yp[8192 x 2048] * W2[1024 x 2048]^T -> G f16
  gemm_bt<0><<<dim3(DM / 128, MROWS / 128), 256, 0, stream>>>(Yp, W2, DI, G, nullptr);

  ln_res<<<MROWS, 256, 0, stream>>>(G, x, ln_g, ln_b, out);
}